// Round 4
// baseline (451.406 us; speedup 1.0000x reference)
//
#include <hip/hip_runtime.h>
#include <math.h>

// Problem constants (fixed by the reference)
constexpr int Bb  = 2;
constexpr int Ss  = 2048;
constexpr int Dd  = 2048;
constexpr int Hh  = 16;
constexpr int DHd = 128;
constexpr int BS  = Bb * Ss;   // 4096
constexpr int NQKV = 2304;     // 2048 q + 128 k + 128 v

typedef __bf16 bf16x8 __attribute__((ext_vector_type(8)));
typedef float  f32x4  __attribute__((ext_vector_type(4)));

// fp32 -> bf16 (RNE), bit-level
static __device__ __forceinline__ unsigned short f2bf(float f) {
  union { float f; unsigned int u; } a; a.f = f;
  unsigned int u = a.u;
  unsigned int r = (u + 0x7fffu + ((u >> 16) & 1u)) >> 16;
  return (unsigned short)r;
}
static __device__ __forceinline__ float bf2f(unsigned short u) {
  union { unsigned int u; float f; } a; a.u = ((unsigned int)u) << 16;
  return a.f;
}
// pack two fp32 -> one dword of 2 bf16 (lo = first)
static __device__ __forceinline__ int pk2bf(float lo, float hi) {
  return (int)((unsigned int)f2bf(lo) | ((unsigned int)f2bf(hi) << 16));
}

// ---------------------------------------------------------------------------
// cast ALL fp32 inputs -> bf16 into one contiguous ws region:
//   [qw (2048x2048) | kvw (256x2048) | ow (2048x2048) | x (4096x2048)]
// float4-per-thread; ranges in float4 units.
// ---------------------------------------------------------------------------
__global__ __launch_bounds__(256) void cast_all(
    const float* __restrict__ qw, const float* __restrict__ kvw,
    const float* __restrict__ ow, const float* __restrict__ x,
    unsigned short* __restrict__ dst)
{
  const int i = blockIdx.x * 256 + threadIdx.x;   // grid sized exactly
  const float* src; int off;
  if (i < 1048576)      { src = qw;  off = 0; }
  else if (i < 1179648) { src = kvw; off = 1048576; }
  else if (i < 2228224) { src = ow;  off = 1179648; }
  else                  { src = x;   off = 2228224; }
  const float4 v = ((const float4*)src)[i - off];
  ushort4 o;
  o.x = f2bf(v.x); o.y = f2bf(v.y); o.z = f2bf(v.z); o.w = f2bf(v.w);
  ((ushort4*)dst)[i] = o;
}

// ---------------------------------------------------------------------------
// bf16 MFMA GEMM: C[M][N] = A[M][K] @ Bw[N][K]^T + bias(col).
// bias(col) = col < nsplit ? bias1[col] : bias2[col-nsplit]  (merged QKV).
// 128x128 tile, BK=32, 256 threads, global_load_lds width-16 staging.
// ---------------------------------------------------------------------------
#define TM 128
#define TN 128
#define TK 32

#define GLOAD16(gp, lp)                                                        \
  __builtin_amdgcn_global_load_lds(                                            \
      (const __attribute__((address_space(1))) void*)(gp),                     \
      (__attribute__((address_space(3))) void*)(lp), 16, 0, 0)

template <bool BF16OUT>
__global__ __launch_bounds__(256) void gemm_bt_mfma(
    const unsigned short* __restrict__ A,    // M x K bf16
    const unsigned short* __restrict__ Bw,   // N x K bf16
    const float* __restrict__ bias1,
    const float* __restrict__ bias2,
    int nsplit,
    void* __restrict__ Cv,                   // M x N (fp32 or bf16)
    int M, int N, int K)
{
  __shared__ unsigned short As[TM * TK];   // 8 KB
  __shared__ unsigned short Bs[TN * TK];   // 8 KB

  const int tid  = threadIdx.x;
  const int w    = tid >> 6;
  const int lane = tid & 63;
  const int m0   = blockIdx.y * TM;
  const int n0   = blockIdx.x * TN;
  const int wm   = (w >> 1) * 64;
  const int wn   = (w & 1) * 64;

  f32x4 acc[4][4];
#pragma unroll
  for (int i = 0; i < 4; i++)
#pragma unroll
    for (int j = 0; j < 4; j++) acc[i][j] = (f32x4){0.f, 0.f, 0.f, 0.f};

  const int srow = lane >> 2;
  const int scol = (lane & 3) * 8;
  const unsigned short* aG0 = A  + (size_t)(m0 +      w * 16 + srow) * K + scol;
  const unsigned short* aG1 = A  + (size_t)(m0 + 64 + w * 16 + srow) * K + scol;
  const unsigned short* bG0 = Bw + (size_t)(n0 +      w * 16 + srow) * K + scol;
  const unsigned short* bG1 = Bw + (size_t)(n0 + 64 + w * 16 + srow) * K + scol;
  unsigned short* aL0 = &As[(     w * 16) * TK];
  unsigned short* aL1 = &As[(64 + w * 16) * TK];
  unsigned short* bL0 = &Bs[(     w * 16) * TK];
  unsigned short* bL1 = &Bs[(64 + w * 16) * TK];

  const int fr = lane & 15;
  const int fk = (lane >> 4) * 8;

  for (int k0 = 0; k0 < K; k0 += TK) {
    __syncthreads();
    GLOAD16(aG0 + k0, aL0);
    GLOAD16(aG1 + k0, aL1);
    GLOAD16(bG0 + k0, bL0);
    GLOAD16(bG1 + k0, bL1);
    __syncthreads();

    bf16x8 af[4], bfr[4];
#pragma unroll
    for (int i = 0; i < 4; i++)
      af[i] = *(const bf16x8*)&As[(wm + i * 16 + fr) * TK + fk];
#pragma unroll
    for (int j = 0; j < 4; j++)
      bfr[j] = *(const bf16x8*)&Bs[(wn + j * 16 + fr) * TK + fk];
#pragma unroll
    for (int i = 0; i < 4; i++)
#pragma unroll
      for (int j = 0; j < 4; j++)
        acc[i][j] = __builtin_amdgcn_mfma_f32_16x16x32_bf16(
            af[i], bfr[j], acc[i][j], 0, 0, 0);
  }

  const int er = (lane >> 4) * 4;
  const int ec = lane & 15;
#pragma unroll
  for (int j = 0; j < 4; j++) {
    const int col = n0 + wn + j * 16 + ec;
    const float bv = (col < nsplit) ? bias1[col] : bias2[col - nsplit];
#pragma unroll
    for (int i = 0; i < 4; i++) {
      const int rbase = m0 + wm + i * 16 + er;
#pragma unroll
      for (int r = 0; r < 4; r++) {
        const float v = acc[i][j][r] + bv;
        if constexpr (BF16OUT)
          ((unsigned short*)Cv)[(size_t)(rbase + r) * N + col] = f2bf(v);
        else
          ((float*)Cv)[(size_t)(rbase + r) * N + col] = v;
      }
    }
  }
}

// ---------------------------------------------------------------------------
// RoPE in-place on q columns of QKV bf16 (B,S,2304). Block per (b,s) row.
// thread t: head t>>4, dims (t&15)*4..+3 paired with +64.
// ---------------------------------------------------------------------------
__global__ __launch_bounds__(256) void rope_q_bf16(unsigned short* __restrict__ QKV)
{
  const int row = blockIdx.x;        // b*S + s
  const int s   = row & (Ss - 1);
  const int t   = threadIdx.x;
  const int h   = t >> 4, p = t & 15;
  unsigned short* base = QKV + (size_t)row * NQKV + h * DHd + p * 4;

  union { ushort4 v; unsigned short a[4]; } lo, hi, olo, ohi;
  lo.v = *(ushort4*)base;
  hi.v = *(ushort4*)(base + 64);
#pragma unroll
  for (int d = 0; d < 4; d++) {
    const int i = p * 4 + d;
    const float invf = exp2f(-(float)i * (13.287712379549449f / 64.0f)); // 10000^(-i/64)
    const float ang = (float)s * invf;
    const float c = cosf(ang), sn = sinf(ang);
    const float l = bf2f(lo.a[d]), hh = bf2f(hi.a[d]);
    olo.a[d] = f2bf(l * c - hh * sn);
    ohi.a[d] = f2bf(hh * c + l * sn);
  }
  *(ushort4*)base        = olo.v;
  *(ushort4*)(base + 64) = ohi.v;
}

// ---------------------------------------------------------------------------
// prep_kv: from QKV bf16 (B,S,2304) — k cols [2048,2176), v cols [2176,2304) —
// produce Kb (B,S,128) roped and Vt (B,128,S) transposed.
// Block per 64 s-rows, 256 threads.
// ---------------------------------------------------------------------------
__global__ __launch_bounds__(256) void prep_kv(
    const unsigned short* __restrict__ QKV,
    unsigned short* __restrict__ Kb,
    unsigned short* __restrict__ Vt)
{
  __shared__ unsigned short Vtile[64 * 136];   // [s_local][d], padded

  const int blk = blockIdx.x;          // b*32 + stile
  const int b   = blk >> 5;
  const int s0  = (blk & 31) * 64;
  const int t   = threadIdx.x;

  // --- rope K
  {
    const int r = t >> 2, p = t & 3;
    const int row = blk * 64 + r;
    const int s = row & (Ss - 1);
    const unsigned short* src = QKV + (size_t)row * NQKV + 2048 + p * 16;
    union { uint4 v[2]; unsigned short a[16]; } lo, hi, ol, oh;
    lo.v[0] = *(const uint4*)src;        lo.v[1] = *(const uint4*)(src + 8);
    hi.v[0] = *(const uint4*)(src + 64); hi.v[1] = *(const uint4*)(src + 72);
#pragma unroll
    for (int e = 0; e < 16; e++) {
      const int i = p * 16 + e;
      const float invf = exp2f(-(float)i * (13.287712379549449f / 64.0f));
      const float ang = (float)s * invf;
      const float c = cosf(ang), sn = sinf(ang);
      const float l = bf2f(lo.a[e]), hh = bf2f(hi.a[e]);
      ol.a[e] = f2bf(l * c - hh * sn);
      oh.a[e] = f2bf(hh * c + l * sn);
    }
    unsigned short* dst = Kb + (size_t)row * 128 + p * 16;
    *(uint4*)dst        = ol.v[0]; *(uint4*)(dst + 8)  = ol.v[1];
    *(uint4*)(dst + 64) = oh.v[0]; *(uint4*)(dst + 72) = oh.v[1];
  }

  // --- stage V into LDS, s-major
#pragma unroll
  for (int c = 0; c < 4; c++) {
    const int id = c * 256 + t;
    const int vr = id >> 4, cc = id & 15;
    *(uint4*)&Vtile[vr * 136 + cc * 8] =
        *(const uint4*)(QKV + (size_t)(blk * 64 + vr) * NQKV + 2176 + cc * 8);
  }
  __syncthreads();

  // --- write Vt rows
  {
    const int d = t >> 1, half = t & 1;
    union { uint4 v[4]; unsigned short a[32]; } val;
#pragma unroll
    for (int kk = 0; kk < 32; kk++)
      val.a[kk] = Vtile[(half * 32 + kk) * 136 + d];
    unsigned short* dst = Vt + ((size_t)(b * 128 + d)) * Ss + s0 + half * 32;
#pragma unroll
    for (int c = 0; c < 4; c++) *(uint4*)(dst + c * 8) = val.v[c];
  }
}

// ---------------------------------------------------------------------------
// flash_v3: causal MQA attention, barrier-free K-loop, max-free softmax.
// Grid (S/32, H, B) = 2048 blocks, 256 threads = 4 waves.
// Block owns 32 q-rows; wave w handles key-tiles kt = w, w+4, ... (32 keys ea).
// All K/V fragments loaded global->register in MFMA layouts.
// S^T = K·Q^T via 16x16x32 MFMA (C: col=lane&15=qrow, row=(lane>>4)*4+r=key).
// P transposed C-layout -> A-layout fully in-register via __shfl.
// Partial O (f32) + l combined across the 4 waves through LDS at block end.
// ---------------------------------------------------------------------------
__global__ __launch_bounds__(256) void flash_v3(
    const unsigned short* __restrict__ QKV,  // (B,S,2304), q roped in [0,2048)
    const unsigned short* __restrict__ Kb,   // (B,S,128) roped
    const unsigned short* __restrict__ Vt,   // (B,128,S)
    unsigned short* __restrict__ attn)       // (B,S,2048) bf16
{
  __shared__ float R0[128 * 36];   // [dh][qrow] padded (18.4 KB)
  __shared__ float R1[128 * 36];
  __shared__ float lb[4][32];
  __shared__ float lf[32];

  const int qt = (int)gridDim.x - 1 - (int)blockIdx.x;  // heavy tiles first
  const int h = blockIdx.y, b = blockIdx.z;
  const int q0 = qt * 32;
  const int tid = threadIdx.x;
  const int w = tid >> 6, lane = tid & 63;
  const int lg = lane >> 4, lm = lane & 15;

  // Q as B-operand fragments: [n=qrow tile nt][k-frag kf]
  // lane: qrow = q0 + nt*16 + lm, dh = kf*32 + lg*8 .. +7
  bf16x8 qf[2][4];
#pragma unroll
  for (int nt = 0; nt < 2; nt++) {
    const unsigned short* qp =
        QKV + (size_t)(b * Ss + q0 + nt * 16 + lm) * NQKV + h * DHd + lg * 8;
#pragma unroll
    for (int kf = 0; kf < 4; kf++) qf[nt][kf] = *(const bf16x8*)(qp + kf * 32);
  }

  // O accumulator C-layout: o[qrow-tile nt][dh-tile dnt]:
  //   qrow = nt*16 + lg*4 + r, dh = dnt*16 + lm
  f32x4 o[2][8];
  float lsum[2] = {0.f, 0.f};   // qrow = nt*16 + lm
#pragma unroll
  for (int nt = 0; nt < 2; nt++)
#pragma unroll
    for (int dnt = 0; dnt < 8; dnt++) o[nt][dnt] = (f32x4){0.f, 0.f, 0.f, 0.f};

  // shfl source lanes for the P transpose (see derivation below)
  const int addr0 = (2 * (lg & 1)) * 16 + lm;   // for dwords d=0,1
  const int addr1 = addr0 + 16;                 // for dwords d=2,3

  const float sscale = 0.08838834764831845f * 1.4426950408889634f; // /sqrt(128)*log2e
  const unsigned short* Kbase = Kb + (size_t)b * Ss * 128;
  const unsigned short* Vbase = Vt + (size_t)b * 128 * Ss;

  for (int kt = w; kt <= qt; kt += 4) {
    const int kbase = kt * 32;

    // K as A-operand frags: [key tile mt][kf]: lane: key = kbase+mt*16+lm,
    // dh = kf*32 + lg*8
    bf16x8 kfr[2][4];
#pragma unroll
    for (int mt = 0; mt < 2; mt++) {
      const unsigned short* kp = Kbase + (size_t)(kbase + mt * 16 + lm) * 128 + lg * 8;
#pragma unroll
      for (int kf = 0; kf < 4; kf++) kfr[mt][kf] = *(const bf16x8*)(kp + kf * 32);
    }
    // V as B-operand frags: [dh tile dnt]: lane: dh = dnt*16+lm, keys kbase+lg*8..+7
    bf16x8 vf[8];
#pragma unroll
    for (int dnt = 0; dnt < 8; dnt++)
      vf[dnt] = *(const bf16x8*)(Vbase + (size_t)(dnt * 16 + lm) * Ss + kbase + lg * 8);

    // ---- QK: S^T[key][qrow]
    f32x4 sc[2][2];
#pragma unroll
    for (int mt = 0; mt < 2; mt++)
#pragma unroll
      for (int nt = 0; nt < 2; nt++) sc[mt][nt] = (f32x4){0.f, 0.f, 0.f, 0.f};
#pragma unroll
    for (int mt = 0; mt < 2; mt++)
#pragma unroll
      for (int nt = 0; nt < 2; nt++)
#pragma unroll
        for (int kf = 0; kf < 4; kf++)
          sc[mt][nt] = __builtin_amdgcn_mfma_f32_16x16x32_bf16(
              kfr[mt][kf], qf[nt][kf], sc[mt][nt], 0, 0, 0);

    // ---- max-free softmax: p = exp2(s*scale*log2e); mask only diagonal tile.
    // value (mt,nt,r): key-within-32 = mt*16+lg*4+r, qrow-within-32 = nt*16+lm
    const int diag = (kt == qt);
    int pk[2][2][2];   // [mt][nt][pair]: dword = bf16(r=2p) | bf16(r=2p+1)<<16
#pragma unroll
    for (int mt = 0; mt < 2; mt++) {
      const int keyb = mt * 16 + lg * 4;
#pragma unroll
      for (int nt = 0; nt < 2; nt++) {
        const int th = nt * 16 + lm;
        float p[4];
#pragma unroll
        for (int r = 0; r < 4; r++) {
          const float ev = exp2f(sc[mt][nt][r] * sscale);
          p[r] = (!diag || (keyb + r <= th)) ? ev : 0.f;
          lsum[nt] += p[r];
        }
        pk[mt][nt][0] = pk2bf(p[0], p[1]);
        pk[mt][nt][1] = pk2bf(p[2], p[3]);
      }
    }

    // ---- transpose P: C-layout -> A-layout, in-register.
    // target lane (lg,lm), dword d holds keys (lg*8+2d, lg*8+2d+1) of qrow lm:
    //   source mt = lg>>1; source lane = (2*(lg&1)+(d>>1))*16 + lm; pair = d&1.
#pragma unroll
    for (int nt = 0; nt < 2; nt++) {
      union { int d[4]; bf16x8 v; } af;
#pragma unroll
      for (int dd = 0; dd < 4; dd++) {
        const int src = (dd < 2) ? addr0 : addr1;
        const int v0 = __shfl(pk[0][nt][dd & 1], src);
        const int v1 = __shfl(pk[1][nt][dd & 1], src);
        af.d[dd] = (lg & 2) ? v1 : v0;
      }
      // ---- PV: O[qrow][dh] += P(16x32) · V(32x128)
#pragma unroll
      for (int dnt = 0; dnt < 8; dnt++)
        o[nt][dnt] = __builtin_amdgcn_mfma_f32_16x16x32_bf16(
            af.v, vf[dnt], o[nt][dnt], 0, 0, 0);
    }
  }

  // ---- reduce lsum over the 4 lg lane-groups (keys split across lg)
#pragma unroll
  for (int nt = 0; nt < 2; nt++) {
    lsum[nt] += __shfl_xor(lsum[nt], 16);
    lsum[nt] += __shfl_xor(lsum[nt], 32);
  }
  if (lg == 0) {
    lb[w][lm]      = lsum[0];
    lb[w][16 + lm] = lsum[1];
  }

  // ---- cross-wave O combine through LDS. Layout R[dh*36 + qrow] (f32x4 rows).
  // Phase 1: w1 -> R0, w3 -> R1.
  if (w == 1 || w == 3) {
    float* R = (w == 1) ? R0 : R1;
#pragma unroll
    for (int nt = 0; nt < 2; nt++)
#pragma unroll
      for (int dnt = 0; dnt < 8; dnt++)
        *(f32x4*)&R[(dnt * 16 + lm) * 36 + nt * 16 + lg * 4] = o[nt][dnt];
  }
  __syncthreads();
  // Phase 2: w0 += R0; w2 += R1 then writes sum to R1; w1 computes lf.
  if (w == 0 || w == 2) {
    float* R = (w == 0) ? R0 : R1;
#pragma unroll
    for (int nt = 0; nt < 2; nt++)
#pragma unroll
      for (int dnt = 0; dnt < 8; dnt++) {
        const f32x4 t = *(const f32x4*)&R[(dnt * 16 + lm) * 36 + nt * 16 + lg * 4];
        o[nt][dnt] += t;
      }
    if (w == 2) {
#pragma unroll
      for (int nt = 0; nt < 2; nt++)
#pragma unroll
        for (int dnt = 0; dnt < 8; dnt++)
          *(f32x4*)&R1[(dnt * 16 + lm) * 36 + nt * 16 + lg * 4] = o[nt][dnt];
    }
  } else if (w == 1 && lane < 32) {
    lf[lane] = lb[0][lane] + lb[1][lane] + lb[2][lane] + lb[3][lane];
  }
  __syncthreads();
  // Phase 3: w0 += R1, writes final to R0.
  if (w == 0) {
#pragma unroll
    for (int nt = 0; nt < 2; nt++)
#pragma unroll
      for (int dnt = 0; dnt < 8; dnt++) {
        const f32x4 t = *(const f32x4*)&R1[(dnt * 16 + lm) * 36 + nt * 16 + lg * 4];
        o[nt][dnt] += t;
        *(f32x4*)&R0[(dnt * 16 + lm) * 36 + nt * 16 + lg * 4] = o[nt][dnt];
      }
  }
  __syncthreads();

  // ---- cooperative normalized store: thread t: qrow = t>>3, dh chunk = (t&7)*16
  {
    const int qrow = tid >> 3, c = tid & 7;
    const float inv = 1.0f / lf[qrow];
    unsigned short* dst =
        attn + (size_t)(b * Ss + q0 + qrow) * Dd + h * DHd + c * 16;
    union { uint4 v[2]; unsigned short a[16]; } ov;
#pragma unroll
    for (int e = 0; e < 16; e++)
      ov.a[e] = f2bf(R0[(c * 16 + e) * 36 + qrow] * inv);
    *(uint4*)dst       = ov.v[0];
    *(uint4*)(dst + 8) = ov.v[1];
  }
}

// ---------------------------------------------------------------------------
extern "C" void kernel_launch(void* const* d_in, const int* in_sizes, int n_in,
                              void* d_out, int out_size, void* d_ws, size_t ws_size,
                              hipStream_t stream) {
  const float* x   = (const float*)d_in[0];   // (B,S,D)
  const float* qw  = (const float*)d_in[1];   // (2048, 2048)
  const float* qb  = (const float*)d_in[2];
  const float* kvw = (const float*)d_in[3];   // (256, 2048)
  const float* kvb = (const float*)d_in[4];
  const float* ow  = (const float*)d_in[5];   // (2048, 2048)
  const float* ob  = (const float*)d_in[6];
  float* out = (float*)d_out;

  // workspace layout (bf16 elements):
  //   wqkv @ 0          (2304 x 2048 = 4,718,592)   qw rows 0-2047, kvw 2048-2303
  //   owb  @ 4,718,592  (2048 x 2048 = 4,194,304)
  //   xb   @ 8,912,896  (4096 x 2048 = 8,388,608)   -> reused as attn_b
  //   QKV  @ 17,301,504 (4096 x 2304 = 9,437,184)
  //   Kb   @ 26,738,688 (4096 x 128  =   524,288)
  //   Vt   @ 27,262,976 (2 x 128 x 2048 = 524,288)
  // total 27,787,264 el = 55.6 MB
  unsigned short* wsb    = (unsigned short*)d_ws;
  unsigned short* wqkv   = wsb;
  unsigned short* owb    = wsb + 4718592;
  unsigned short* xb     = wsb + 8912896;
  unsigned short* attn_b = xb;                 // alias: xb dead after QKV gemm
  unsigned short* QKV    = wsb + 17301504;
  unsigned short* Kb     = wsb + 26738688;
  unsigned short* Vt     = wsb + 27262976;

  // 1. all fp32->bf16 casts in one kernel (dst regions are contiguous)
  cast_all<<<16896, 256, 0, stream>>>(qw, kvw, ow, x, wqkv);

  // 2. merged QKV projection: (4096 x 2304) = xb @ wqkv^T + [qb|kvb]
  gemm_bt_mfma<true><<<dim3(NQKV / TN, BS / TM), 256, 0, stream>>>(
      xb, wqkv, qb, kvb, 2048, QKV, BS, NQKV, Dd);

  // 3. RoPE q in-place; 4. K rope + V transpose
  rope_q_bf16<<<BS, 256, 0, stream>>>(QKV);
  prep_kv<<<BS / 64, 256, 0, stream>>>(QKV, Kb, Vt);

  // 5. flash attention
  flash_v3<<<dim3(Ss / 32, Hh, Bb), 256, 0, stream>>>(QKV, Kb, Vt, attn_b);

  // 6. O projection: out = attn @ ow^T + ob (fp32 out)
  gemm_bt_mfma<false><<<dim3(Dd / TN, BS / TM), 256, 0, stream>>>(
      attn_b, owb, ob, ob, Dd, out, BS, Dd, Dd);
}

// Round 5
// 364.023 us; speedup vs baseline: 1.2400x; 1.2400x over previous
//
#include <hip/hip_runtime.h>
#include <math.h>

// Problem constants (fixed by the reference)
constexpr int Bb  = 2;
constexpr int Ss  = 2048;
constexpr int Dd  = 2048;
constexpr int Hh  = 16;
constexpr int DHd = 128;
constexpr int BS  = Bb * Ss;   // 4096
constexpr int NQKV = 2304;     // 2048 q + 128 k + 128 v

typedef __bf16 bf16x8 __attribute__((ext_vector_type(8)));
typedef float  f32x4  __attribute__((ext_vector_type(4)));

// fp32 -> bf16 (RNE), bit-level
static __device__ __forceinline__ unsigned short f2bf(float f) {
  union { float f; unsigned int u; } a; a.f = f;
  unsigned int u = a.u;
  unsigned int r = (u + 0x7fffu + ((u >> 16) & 1u)) >> 16;
  return (unsigned short)r;
}
static __device__ __forceinline__ float bf2f(unsigned short u) {
  union { unsigned int u; float f; } a; a.u = ((unsigned int)u) << 16;
  return a.f;
}
// pack two fp32 -> one dword of 2 bf16 (lo = first)
static __device__ __forceinline__ int pk2bf(float lo, float hi) {
  return (int)((unsigned int)f2bf(lo) | ((unsigned int)f2bf(hi) << 16));
}
static __device__ __forceinline__ f32x4 mfma16(bf16x8 a, bf16x8 b, f32x4 c) {
  return __builtin_amdgcn_mfma_f32_16x16x32_bf16(a, b, c, 0, 0, 0);
}

// ---------------------------------------------------------------------------
// cast ALL fp32 inputs -> bf16 into one contiguous ws region:
//   [qw (2048x2048) | kvw (256x2048) | ow (2048x2048) | x (4096x2048)]
// ---------------------------------------------------------------------------
__global__ __launch_bounds__(256) void cast_all(
    const float* __restrict__ qw, const float* __restrict__ kvw,
    const float* __restrict__ ow, const float* __restrict__ x,
    unsigned short* __restrict__ dst)
{
  const int i = blockIdx.x * 256 + threadIdx.x;   // grid sized exactly
  const float* src; int off;
  if (i < 1048576)      { src = qw;  off = 0; }
  else if (i < 1179648) { src = kvw; off = 1048576; }
  else if (i < 2228224) { src = ow;  off = 1179648; }
  else                  { src = x;   off = 2228224; }
  const float4 v = ((const float4*)src)[i - off];
  ushort4 o;
  o.x = f2bf(v.x); o.y = f2bf(v.y); o.z = f2bf(v.z); o.w = f2bf(v.w);
  ((ushort4*)dst)[i] = o;
}

// ---------------------------------------------------------------------------
// bf16 MFMA GEMM: C[M][N] = A[M][K] @ Bw[N][K]^T + bias(col).
// bias(col) = col < nsplit ? bias1[col] : bias2[col-nsplit]  (merged QKV).
// 128x128 tile, BK=32, 256 threads, global_load_lds width-16 staging.
// ---------------------------------------------------------------------------
#define TM 128
#define TN 128
#define TK 32

#define GLOAD16(gp, lp)                                                        \
  __builtin_amdgcn_global_load_lds(                                            \
      (const __attribute__((address_space(1))) void*)(gp),                     \
      (__attribute__((address_space(3))) void*)(lp), 16, 0, 0)

template <bool BF16OUT>
__global__ __launch_bounds__(256) void gemm_bt_mfma(
    const unsigned short* __restrict__ A,    // M x K bf16
    const unsigned short* __restrict__ Bw,   // N x K bf16
    const float* __restrict__ bias1,
    const float* __restrict__ bias2,
    int nsplit,
    void* __restrict__ Cv,                   // M x N (fp32 or bf16)
    int M, int N, int K)
{
  __shared__ unsigned short As[TM * TK];   // 8 KB
  __shared__ unsigned short Bs[TN * TK];   // 8 KB

  const int tid  = threadIdx.x;
  const int w    = tid >> 6;
  const int lane = tid & 63;
  const int m0   = blockIdx.y * TM;
  const int n0   = blockIdx.x * TN;
  const int wm   = (w >> 1) * 64;
  const int wn   = (w & 1) * 64;

  f32x4 acc[4][4];
#pragma unroll
  for (int i = 0; i < 4; i++)
#pragma unroll
    for (int j = 0; j < 4; j++) acc[i][j] = (f32x4){0.f, 0.f, 0.f, 0.f};

  const int srow = lane >> 2;
  const int scol = (lane & 3) * 8;
  const unsigned short* aG0 = A  + (size_t)(m0 +      w * 16 + srow) * K + scol;
  const unsigned short* aG1 = A  + (size_t)(m0 + 64 + w * 16 + srow) * K + scol;
  const unsigned short* bG0 = Bw + (size_t)(n0 +      w * 16 + srow) * K + scol;
  const unsigned short* bG1 = Bw + (size_t)(n0 + 64 + w * 16 + srow) * K + scol;
  unsigned short* aL0 = &As[(     w * 16) * TK];
  unsigned short* aL1 = &As[(64 + w * 16) * TK];
  unsigned short* bL0 = &Bs[(     w * 16) * TK];
  unsigned short* bL1 = &Bs[(64 + w * 16) * TK];

  const int fr = lane & 15;
  const int fk = (lane >> 4) * 8;

  for (int k0 = 0; k0 < K; k0 += TK) {
    __syncthreads();
    GLOAD16(aG0 + k0, aL0);
    GLOAD16(aG1 + k0, aL1);
    GLOAD16(bG0 + k0, bL0);
    GLOAD16(bG1 + k0, bL1);
    __syncthreads();

    bf16x8 af[4], bfr[4];
#pragma unroll
    for (int i = 0; i < 4; i++)
      af[i] = *(const bf16x8*)&As[(wm + i * 16 + fr) * TK + fk];
#pragma unroll
    for (int j = 0; j < 4; j++)
      bfr[j] = *(const bf16x8*)&Bs[(wn + j * 16 + fr) * TK + fk];
#pragma unroll
    for (int i = 0; i < 4; i++)
#pragma unroll
      for (int j = 0; j < 4; j++)
        acc[i][j] = mfma16(af[i], bfr[j], acc[i][j]);
  }

  const int er = (lane >> 4) * 4;
  const int ec = lane & 15;
#pragma unroll
  for (int j = 0; j < 4; j++) {
    const int col = n0 + wn + j * 16 + ec;
    const float bv = (col < nsplit) ? bias1[col] : bias2[col - nsplit];
#pragma unroll
    for (int i = 0; i < 4; i++) {
      const int rbase = m0 + wm + i * 16 + er;
#pragma unroll
      for (int r = 0; r < 4; r++) {
        const float v = acc[i][j][r] + bv;
        if constexpr (BF16OUT)
          ((unsigned short*)Cv)[(size_t)(rbase + r) * N + col] = f2bf(v);
        else
          ((float*)Cv)[(size_t)(rbase + r) * N + col] = v;
      }
    }
  }
}

// ---------------------------------------------------------------------------
// RoPE in-place on q columns of QKV bf16 (B,S,2304).
// ---------------------------------------------------------------------------
__global__ __launch_bounds__(256) void rope_q_bf16(unsigned short* __restrict__ QKV)
{
  const int row = blockIdx.x;        // b*S + s
  const int s   = row & (Ss - 1);
  const int t   = threadIdx.x;
  const int h   = t >> 4, p = t & 15;
  unsigned short* base = QKV + (size_t)row * NQKV + h * DHd + p * 4;

  union { ushort4 v; unsigned short a[4]; } lo, hi, olo, ohi;
  lo.v = *(ushort4*)base;
  hi.v = *(ushort4*)(base + 64);
#pragma unroll
  for (int d = 0; d < 4; d++) {
    const int i = p * 4 + d;
    const float invf = exp2f(-(float)i * (13.287712379549449f / 64.0f)); // 10000^(-i/64)
    const float ang = (float)s * invf;
    const float c = cosf(ang), sn = sinf(ang);
    const float l = bf2f(lo.a[d]), hh = bf2f(hi.a[d]);
    olo.a[d] = f2bf(l * c - hh * sn);
    ohi.a[d] = f2bf(hh * c + l * sn);
  }
  *(ushort4*)base        = olo.v;
  *(ushort4*)(base + 64) = ohi.v;
}

// ---------------------------------------------------------------------------
// prep_kv: from QKV bf16 (B,S,2304) — k cols [2048,2176), v cols [2176,2304) —
// produce Kb (B,S,128) roped and Vt (B,128,S) transposed.
// ---------------------------------------------------------------------------
__global__ __launch_bounds__(256) void prep_kv(
    const unsigned short* __restrict__ QKV,
    unsigned short* __restrict__ Kb,
    unsigned short* __restrict__ Vt)
{
  __shared__ unsigned short Vtile[64 * 136];   // [s_local][d], padded

  const int blk = blockIdx.x;          // b*32 + stile
  const int b   = blk >> 5;
  const int s0  = (blk & 31) * 64;
  const int t   = threadIdx.x;

  // --- rope K
  {
    const int r = t >> 2, p = t & 3;
    const int row = blk * 64 + r;
    const int s = row & (Ss - 1);
    const unsigned short* src = QKV + (size_t)row * NQKV + 2048 + p * 16;
    union { uint4 v[2]; unsigned short a[16]; } lo, hi, ol, oh;
    lo.v[0] = *(const uint4*)src;        lo.v[1] = *(const uint4*)(src + 8);
    hi.v[0] = *(const uint4*)(src + 64); hi.v[1] = *(const uint4*)(src + 72);
#pragma unroll
    for (int e = 0; e < 16; e++) {
      const int i = p * 16 + e;
      const float invf = exp2f(-(float)i * (13.287712379549449f / 64.0f));
      const float ang = (float)s * invf;
      const float c = cosf(ang), sn = sinf(ang);
      const float l = bf2f(lo.a[e]), hh = bf2f(hi.a[e]);
      ol.a[e] = f2bf(l * c - hh * sn);
      oh.a[e] = f2bf(hh * c + l * sn);
    }
    unsigned short* dst = Kb + (size_t)row * 128 + p * 16;
    *(uint4*)dst        = ol.v[0]; *(uint4*)(dst + 8)  = ol.v[1];
    *(uint4*)(dst + 64) = oh.v[0]; *(uint4*)(dst + 72) = oh.v[1];
  }

  // --- stage V into LDS, s-major
#pragma unroll
  for (int c = 0; c < 4; c++) {
    const int id = c * 256 + t;
    const int vr = id >> 4, cc = id & 15;
    *(uint4*)&Vtile[vr * 136 + cc * 8] =
        *(const uint4*)(QKV + (size_t)(blk * 64 + vr) * NQKV + 2176 + cc * 8);
  }
  __syncthreads();

  // --- write Vt rows
  {
    const int d = t >> 1, half = t & 1;
    union { uint4 v[4]; unsigned short a[32]; } val;
#pragma unroll
    for (int kk = 0; kk < 32; kk++)
      val.a[kk] = Vtile[(half * 32 + kk) * 136 + d];
    unsigned short* dst = Vt + ((size_t)(b * 128 + d)) * Ss + s0 + half * 32;
#pragma unroll
    for (int c = 0; c < 4; c++) *(uint4*)(dst + c * 8) = val.v[c];
  }
}

// ---------------------------------------------------------------------------
// flash_v5: causal MQA attention, m97-style staged MFMA, max-free softmax.
// Grid (S/64, H, B) = 1024 blocks, 256 threads = 4 waves; wave w owns q-rows
// q0+w*16..+15 (q-split: no cross-wave combine).
// LDS: K in 4 dh-panels [64 keys x 32 dh] (64B rows), V in 2 key-panels
// [128 dh x 32 keys] (64B rows) -> m97 frag-read geometry, filled by
// global_load_lds width-16 (8 per wave per 64-key iteration).
// S^T = K·Q^T (C: col=lm=qrow, row=4lg+r=key); p=exp2(s*scale) (max-free);
// P^T C-layout -> B-layout via 8 bpermutes per 32-key half; O^T = V^T·P^T.
// ---------------------------------------------------------------------------
__global__ __launch_bounds__(256, 4) void flash_v5(
    const unsigned short* __restrict__ QKV,  // (B,S,2304), q roped in [0,2048)
    const unsigned short* __restrict__ Kb,   // (B,S,128) roped
    const unsigned short* __restrict__ Vt,   // (B,128,S)
    unsigned short* __restrict__ attn)       // (B,S,2048) bf16
{
  __shared__ unsigned short Ks[4 * 64 * 32];   // panel kf: [key][dh32], 16 KB
  __shared__ unsigned short Vs[2 * 128 * 32];  // panel ks2: [dh][key32], 16 KB

  const int qt = 31 - (int)blockIdx.x;         // heavy tiles first
  const int h = blockIdx.y, b = blockIdx.z;
  const int q0 = qt * 64;
  const int tid = threadIdx.x;
  const int w = tid >> 6, lane = tid & 63;
  const int lg = lane >> 4, lm = lane & 15;
  const int qrow = q0 + w * 16 + lm;           // this lane's q-row
  const int qrow_hi = q0 + w * 16 + 15;        // wave's last q-row

  // Q as B-operand frags: [kf]: lane: n=qrow(lm), k = kf*32 + lg*8 + j (dh)
  bf16x8 qf[4];
  {
    const unsigned short* qp =
        QKV + (size_t)(b * Ss + qrow) * NQKV + h * DHd + lg * 8;
#pragma unroll
    for (int kf = 0; kf < 4; kf++) qf[kf] = *(const bf16x8*)(qp + kf * 32);
  }

  // O^T accumulator, C-layout: element (dh = dt*16 + 4*lg + r, qrow = lm)
  f32x4 ot[8];
#pragma unroll
  for (int dt = 0; dt < 8; dt++) ot[dt] = (f32x4){0.f, 0.f, 0.f, 0.f};
  float lsum = 0.f;

  const float sscale = 0.08838834764831845f * 1.4426950408889634f; // /sqrt(128)*log2e

  // staging lane addresses
  const int sr  = lane >> 2;          // row-within-16
  const int sc8 = (lane & 3) * 8;     // 16B chunk
  const unsigned short* kg =
      Kb + (size_t)b * Ss * 128 + (size_t)sr * 128 + w * 32 + sc8;
  const unsigned short* vg =
      Vt + (size_t)b * 128 * Ss + (size_t)(w * 32 + sr) * Ss + sc8;
  unsigned short* ksl  = &Ks[w * 2048];             // panel w (dh w*32..+31)
  unsigned short* vsl0 = &Vs[(w * 32) * 32];        // ks2=0, dh rows w*32..
  unsigned short* vsl1 = &Vs[4096 + (w * 32) * 32]; // ks2=1

  // transpose shuffle sources (C->B layout, within a 32-key half)
  const int addr0 = (2 * (lg & 1)) * 16 + lm;   // dwords 0,1
  const int addr1 = addr0 + 16;                 // dwords 2,3
  const bool sel_hi = (lg & 2) != 0;

  // one 32-key half: S^T tiles tA,tA+1 -> exp -> transpose -> PV on panel VsP
  auto half32 = [&](int keybase, int tA, const unsigned short* VsP) {
    f32x4 s[2];
    s[0] = (f32x4){0.f, 0.f, 0.f, 0.f};
    s[1] = (f32x4){0.f, 0.f, 0.f, 0.f};
#pragma unroll
    for (int kf = 0; kf < 4; kf++) {
      const bf16x8 k0 = *(const bf16x8*)&Ks[kf * 2048 + ((tA)     * 16 + lm) * 32 + lg * 8];
      const bf16x8 k1 = *(const bf16x8*)&Ks[kf * 2048 + ((tA + 1) * 16 + lm) * 32 + lg * 8];
      s[0] = mfma16(k0, qf[kf], s[0]);
      s[1] = mfma16(k1, qf[kf], s[1]);
    }
    // mask + exp2 (max-free) + pack
    int pk[2][2];
#pragma unroll
    for (int t = 0; t < 2; t++) {
      float p[4];
#pragma unroll
      for (int r = 0; r < 4; r++) {
        const int key = keybase + t * 16 + 4 * lg + r;
        const float ev = exp2f(s[t][r] * sscale);
        p[r] = (key <= qrow) ? ev : 0.f;
        lsum += p[r];
      }
      pk[t][0] = pk2bf(p[0], p[1]);
      pk[t][1] = pk2bf(p[2], p[3]);
    }
    // C-layout -> B-layout transpose (8 bpermutes)
    union { int d[4]; bf16x8 v; } pb;
#pragma unroll
    for (int d = 0; d < 4; d++) {
      const int src = (d < 2) ? addr0 : addr1;
      const int v0 = __shfl(pk[0][d & 1], src);
      const int v1 = __shfl(pk[1][d & 1], src);
      pb.d[d] = sel_hi ? v1 : v0;
    }
    // O^T += V^T(32 keys) · P^T
#pragma unroll
    for (int dt = 0; dt < 8; dt++) {
      const bf16x8 vfrag = *(const bf16x8*)&VsP[(dt * 16 + lm) * 32 + lg * 8];
      ot[dt] = mfma16(vfrag, pb.v, ot[dt]);
    }
  };

  for (int j0 = 0; j0 <= q0; j0 += 64) {
    __syncthreads();            // previous iteration's LDS readers done
    // stage K panel w (dh w*32..+31, keys j0..j0+63): 4 x 1KB
#pragma unroll
    for (int i = 0; i < 4; i++)
      GLOAD16(kg + (size_t)(j0 + i * 16) * 128, ksl + i * 512);
    // stage V dh-rows w*32..+31, both key panels: 4 x 1KB
#pragma unroll
    for (int i = 0; i < 2; i++) {
      GLOAD16(vg + (size_t)(i * 16) * Ss + j0,      vsl0 + i * 512);
      GLOAD16(vg + (size_t)(i * 16) * Ss + j0 + 32, vsl1 + i * 512);
    }
    __syncthreads();            // vmcnt(0) drained before use

    half32(j0, 0, &Vs[0]);                      // keys j0..j0+31
    if (j0 + 32 <= qrow_hi)                     // wave-uniform skip
      half32(j0 + 32, 2, &Vs[4096]);            // keys j0+32..j0+63
  }

  // reduce lsum over the 4 lg groups (same lm = same qrow)
  lsum += __shfl_xor(lsum, 16);
  lsum += __shfl_xor(lsum, 32);
  const float inv = 1.0f / lsum;

  // store: lane covers (qrow, dh = dt*16 + 4lg + 0..3)
  unsigned short* dst = attn + (size_t)(b * Ss + qrow) * Dd + h * DHd + lg * 4;
#pragma unroll
  for (int dt = 0; dt < 8; dt++) {
    ushort4 o4;
    o4.x = f2bf(ot[dt][0] * inv);
    o4.y = f2bf(ot[dt][1] * inv);
    o4.z = f2bf(ot[dt][2] * inv);
    o4.w = f2bf(ot[dt][3] * inv);
    *(ushort4*)(dst + dt * 16) = o4;
  }
}

// ---------------------------------------------------------------------------
extern "C" void kernel_launch(void* const* d_in, const int* in_sizes, int n_in,
                              void* d_out, int out_size, void* d_ws, size_t ws_size,
                              hipStream_t stream) {
  const float* x   = (const float*)d_in[0];   // (B,S,D)
  const float* qw  = (const float*)d_in[1];   // (2048, 2048)
  const float* qb  = (const float*)d_in[2];
  const float* kvw = (const float*)d_in[3];   // (256, 2048)
  const float* kvb = (const float*)d_in[4];
  const float* ow  = (const float*)d_in[5];   // (2048, 2048)
  const float* ob  = (const float*)d_in[6];
  float* out = (float*)d_out;

  // workspace layout (bf16 elements):
  //   wqkv @ 0          (2304 x 2048)   qw rows 0-2047, kvw 2048-2303
  //   owb  @ 4,718,592  (2048 x 2048)
  //   xb   @ 8,912,896  (4096 x 2048)   -> reused as attn_b
  //   QKV  @ 17,301,504 (4096 x 2304)
  //   Kb   @ 26,738,688 (4096 x 128)
  //   Vt   @ 27,262,976 (2 x 128 x 2048)
  unsigned short* wsb    = (unsigned short*)d_ws;
  unsigned short* wqkv   = wsb;
  unsigned short* owb    = wsb + 4718592;
  unsigned short* xb     = wsb + 8912896;
  unsigned short* attn_b = xb;                 // alias: xb dead after QKV gemm
  unsigned short* QKV    = wsb + 17301504;
  unsigned short* Kb     = wsb + 26738688;
  unsigned short* Vt     = wsb + 27262976;

  // 1. all fp32->bf16 casts in one kernel
  cast_all<<<16896, 256, 0, stream>>>(qw, kvw, ow, x, wqkv);

  // 2. merged QKV projection: (4096 x 2304) = xb @ wqkv^T + [qb|kvb]
  gemm_bt_mfma<true><<<dim3(NQKV / TN, BS / TM), 256, 0, stream>>>(
      xb, wqkv, qb, kvb, 2048, QKV, BS, NQKV, Dd);

  // 3. RoPE q in-place; 4. K rope + V transpose
  rope_q_bf16<<<BS, 256, 0, stream>>>(QKV);
  prep_kv<<<BS / 64, 256, 0, stream>>>(QKV, Kb, Vt);

  // 5. flash attention (m97-style staged)
  flash_v5<<<dim3(Ss / 64, Hh, Bb), 256, 0, stream>>>(QKV, Kb, Vt, attn_b);

  // 6. O projection: out = attn @ ow^T + ob (fp32 out)
  gemm_bt_mfma<false><<<dim3(Dd / TN, BS / TM), 256, 0, stream>>>(
      attn_b, owb, ob, ob, Dd, out, BS, Dd, Dd);
}